// Round 10
// baseline (130.323 us; speedup 1.0000x reference)
//
#include <hip/hip_runtime.h>

#define NN   8192
#define DIM  128

// ---- workspace layout (bytes) ----
#define OFF_HB    0UL          // ushort Hb[8192][128] (bf16)  2,097,152
#define OFF_ASRC  2097152UL    // float asrc[8192]                32,768
#define OFF_ADST  2129920UL    // float adst[8192]                32,768
#define WS_NEEDED 2162688UL

#define ROW_CAP  256   // max neighbors/row (mean 82; 19-sigma headroom)

__device__ __forceinline__ unsigned short f2bf(float f) {  // RNE
    unsigned int u = __builtin_bit_cast(unsigned int, f);
    u += 0x7fffu + ((u >> 16) & 1u);
    return (unsigned short)(u >> 16);
}
__device__ __forceinline__ float bf2f(unsigned short s) {
    return __builtin_bit_cast(float, (unsigned int)s << 16);
}

// ---------------------------------------------------------------------------
// K_A gemm+alpha (verified R9 body):
//   [0, 256)   gemm:  Hb = bf16(x W^T), 64x64 tiles, 8.7 KB LDS k-tiled
//   [256, 288) alpha: asrc = x (W^T att_s), adst = x (W^T att_d)
// ---------------------------------------------------------------------------
__global__ __launch_bounds__(256, 8) void k_gemm_alpha(
    const float* __restrict__ x, const float* __restrict__ w,
    const float* __restrict__ att_s, const float* __restrict__ att_d,
    unsigned short* __restrict__ Hb, float* __restrict__ asrc,
    float* __restrict__ adst)
{
    __shared__ union {
        struct { float xa[64][17]; float wb[16][68]; } g;   // 8704 B
        struct { float vs[128]; float vd[128]; } a;         // 1024 B
    } sm;

    const int tid = threadIdx.x;
    const int b   = blockIdx.x;

    if (b < 256) {
        const int i0g = (b >> 1) * 64;
        const int o0  = (b & 1) * 64;
        const int tx  = tid & 15;
        const int ty  = tid >> 4;
        float acc[4][4];
#pragma unroll
        for (int i = 0; i < 4; ++i)
#pragma unroll
            for (int j = 0; j < 4; ++j) acc[i][j] = 0.f;

        for (int kt = 0; kt < 8; ++kt) {   // 8 k-tiles of 16
            __syncthreads();
            {   // stage x: 64 rows x 16 k
                const int r  = tid >> 2;
                const int kq = tid & 3;
                float4 v = *reinterpret_cast<const float4*>(
                    x + (size_t)(i0g + r) * DIM + kt * 16 + kq * 4);
                sm.g.xa[r][kq * 4 + 0] = v.x;
                sm.g.xa[r][kq * 4 + 1] = v.y;
                sm.g.xa[r][kq * 4 + 2] = v.z;
                sm.g.xa[r][kq * 4 + 3] = v.w;
            }
            {   // stage W^T: 16 k x 64 cols (transpose on write)
                const int o  = tid & 63;
                const int kq = tid >> 6;
                float4 v = *reinterpret_cast<const float4*>(
                    w + (size_t)(o0 + o) * DIM + kt * 16 + kq * 4);
                sm.g.wb[kq * 4 + 0][o] = v.x;
                sm.g.wb[kq * 4 + 1][o] = v.y;
                sm.g.wb[kq * 4 + 2][o] = v.z;
                sm.g.wb[kq * 4 + 3][o] = v.w;
            }
            __syncthreads();
#pragma unroll
            for (int kk = 0; kk < 16; ++kk) {
                float4 wv4 = *reinterpret_cast<const float4*>(&sm.g.wb[kk][tx * 4]);
#pragma unroll
                for (int i = 0; i < 4; ++i) {
                    const float xv = sm.g.xa[ty * 4 + i][kk];
                    acc[i][0] += xv * wv4.x;
                    acc[i][1] += xv * wv4.y;
                    acc[i][2] += xv * wv4.z;
                    acc[i][3] += xv * wv4.w;
                }
            }
        }
#pragma unroll
        for (int i = 0; i < 4; ++i) {
            ushort4 h4;
            h4.x = f2bf(acc[i][0]);
            h4.y = f2bf(acc[i][1]);
            h4.z = f2bf(acc[i][2]);
            h4.w = f2bf(acc[i][3]);
            *reinterpret_cast<ushort4*>(
                Hb + (size_t)(i0g + ty * 4 + i) * DIM + o0 + tx * 4) = h4;
        }

    } else {
        const int t = b - 256;             // 0..31
        {   // v = W^T att  (waves 0-1: src, 2-3: dst)
            const int is_d = tid >> 7;
            const int k    = tid & 127;
            const float* av = is_d ? att_d : att_s;
            float acc = 0.f;
            for (int o = 0; o < 128; ++o)
                acc += w[(size_t)o * 128 + k] * av[o];
            (is_d ? sm.a.vd : sm.a.vs)[k] = acc;
        }
        __syncthreads();
        const int r = t * 256 + tid;
        const float4* xr = reinterpret_cast<const float4*>(x + (size_t)r * DIM);
        float ss = 0.f, dd = 0.f;
#pragma unroll 8
        for (int q = 0; q < 32; ++q) {
            float4 xv = xr[q];
#pragma unroll
            for (int e = 0; e < 4; ++e) {
                const int k = q * 4 + e;
                const float xk = (&xv.x)[e];
                ss += xk * sm.a.vs[k];
                dd += xk * sm.a.vd[k];
            }
        }
        asrc[r] = ss;
        adst[r] = dd;
    }
}

// ---------------------------------------------------------------------------
// K_B fused stream+gather: 512 blocks x 512 threads; block owns 16 output
// rows (= 16 adj columns).
//  Phase A: stream the whole adj column-slab (one 64 B line per j per block,
//           each line consumed exactly once device-wide) -> bitmasks in LDS.
//           Task t=(g,q): 32 j's x 4 cols; lanes 4k..4k+3 read one full line.
//  Phase B: per wave x 2 rows (8 waves): popcount -> scan -> ctz extract ->
//           exp weights -> butterfly denom -> dual-neighbor bf16 gather.
//           (verified R9 K2 body, fed from LDS instead of global mask)
// ---------------------------------------------------------------------------
__global__ __launch_bounds__(512, 2) void k_stream_gather(
    const float* __restrict__ adj, const unsigned short* __restrict__ Hb,
    const float* __restrict__ asrc, const float* __restrict__ adst,
    float* __restrict__ out)
{
    __shared__ unsigned int mt[16][260];   // [local col][g], padded stride
    __shared__ int   s_jl[8][257];
    __shared__ float s_wl[8][257];

    const int tid  = threadIdx.x;
    const int b    = blockIdx.x;
    const int lane = tid & 63;
    const int wv   = tid >> 6;
    const int i0   = b * 16;

    // ================= Phase A: stream adj -> LDS bitmasks =================
#pragma unroll
    for (int r = 0; r < 2; ++r) {
        const int tau = tid + (r << 9);    // 0..1023
        const int g   = tau >> 2;          // j-chunk
        const int q   = tau & 3;           // 4-col group
        const float* p = adj + (size_t)(g * 32) * NN + i0 + q * 4;

        unsigned int m0 = 0, m1 = 0, m2 = 0, m3 = 0;
#pragma unroll 8
        for (int jj = 0; jj < 32; ++jj) {
            float4 v = *reinterpret_cast<const float4*>(p + (size_t)jj * NN);
            const unsigned int bb = 1u << jj;
            if (v.x != 0.f) m0 |= bb;
            if (v.y != 0.f) m1 |= bb;
            if (v.z != 0.f) m2 |= bb;
            if (v.w != 0.f) m3 |= bb;
        }
        mt[q * 4 + 0][g] = m0;
        mt[q * 4 + 1][g] = m1;
        mt[q * 4 + 2][g] = m2;
        mt[q * 4 + 3][g] = m3;
    }
    __syncthreads();

    // ================= Phase B: per-wave gather (2 rows each) ==============
    int* const   jl = s_jl[wv];
    float* const wl = s_wl[wv];

    for (int rr = 0; rr < 2; ++rr) {
        const int ii = wv * 2 + rr;
        const int i  = i0 + ii;

        uint4 mv = *reinterpret_cast<const uint4*>(&mt[ii][4 * lane]);
        const int csum = __popc(mv.x) + __popc(mv.y) + __popc(mv.z) + __popc(mv.w);

        int incl = csum;
#pragma unroll
        for (int off = 1; off < 64; off <<= 1) {
            int tt = __shfl_up(incl, off);
            if (lane >= off) incl += tt;
        }
        const int cnt = min(__shfl(incl, 63), ROW_CAP);
        int off = incl - csum;

#define EXTRACT(mm, q)                                                  \
        {                                                               \
            unsigned int z = (mm);                                      \
            const int jb = (4 * lane + (q)) * 32;                       \
            while (z) {                                                 \
                const int bb = __builtin_ctz(z);                        \
                z &= z - 1;                                             \
                if (off < ROW_CAP) jl[off] = jb + bb;                   \
                ++off;                                                  \
            }                                                           \
        }
        EXTRACT(mv.x, 0) EXTRACT(mv.y, 1) EXTRACT(mv.z, 2) EXTRACT(mv.w, 3)
#undef EXTRACT
        __builtin_amdgcn_wave_barrier();

        // weights + denominator
        const float adst_i = adst[i];
        float dsum = 0.f;
        for (int t = lane; t < cnt; t += 64) {
            const float cv = asrc[jl[t]] + adst_i;
            const float wgt = __expf(fmaxf(0.2f * cv, cv));
            wl[t] = wgt;
            dsum += wgt;
        }
#pragma unroll
        for (int mo = 1; mo < 64; mo <<= 1) dsum += __shfl_xor(dsum, mo);
        const float inv = 1.f / dsum;       // self-loops guarantee > 0

        // pad to even count (extra slot weight 0)
        if (lane == 0 && (cnt & 1)) { jl[cnt] = i; wl[cnt] = 0.f; }
        __builtin_amdgcn_wave_barrier();
        const int cnt2 = (cnt + 1) & ~1;

        // dual-neighbor gather: lanes 0-31 even k, 32-63 odd k (bf16 rows)
        const int half = lane >> 5;
        const int l32  = lane & 31;
        float4 acc = make_float4(0.f, 0.f, 0.f, 0.f);
        for (int k = 0; k < cnt2; k += 2) {
            const int   j  = jl[k + half];
            const float ww = wl[k + half];
            ushort4 h = *reinterpret_cast<const ushort4*>(Hb + (size_t)j * DIM + l32 * 4);
            acc.x += ww * bf2f(h.x);
            acc.y += ww * bf2f(h.y);
            acc.z += ww * bf2f(h.z);
            acc.w += ww * bf2f(h.w);
        }
        acc.x += __shfl_xor(acc.x, 32);
        acc.y += __shfl_xor(acc.y, 32);
        acc.z += __shfl_xor(acc.z, 32);
        acc.w += __shfl_xor(acc.w, 32);
        if (half == 0)
            *reinterpret_cast<float4*>(out + (size_t)i * DIM + l32 * 4) =
                make_float4(acc.x * inv, acc.y * inv, acc.z * inv, acc.w * inv);
    }
}

extern "C" void kernel_launch(void* const* d_in, const int* in_sizes, int n_in,
                              void* d_out, int out_size, void* d_ws, size_t ws_size,
                              hipStream_t stream)
{
    const float* x     = (const float*)d_in[0];
    const float* adj   = (const float*)d_in[1];
    const float* w     = (const float*)d_in[2];
    const float* att_s = (const float*)d_in[3];
    const float* att_d = (const float*)d_in[4];
    float* out = (float*)d_out;

    if (ws_size < WS_NEEDED) return;  // loud failure (output stays poisoned)

    char* ws = (char*)d_ws;
    unsigned short* Hb   = (unsigned short*)(ws + OFF_HB);
    float*          asrc = (float*)(ws + OFF_ASRC);
    float*          adst = (float*)(ws + OFF_ADST);

    k_gemm_alpha    <<<288, 256, 0, stream>>>(x, w, att_s, att_d, Hb, asrc, adst);
    k_stream_gather <<<512, 512, 0, stream>>>(adj, Hb, asrc, adst, out);
}

// Round 11
// 90.585 us; speedup vs baseline: 1.4387x; 1.4387x over previous
//
#include <hip/hip_runtime.h>

#define NN   8192
#define DIM  128

// ---- workspace layout (bytes) ----
#define OFF_HB    0UL          // ushort Hb[8192][128] (bf16)  2,097,152
#define OFF_ASRC  2097152UL    // float asrc[8192]                32,768
#define OFF_ADST  2129920UL    // float adst[8192]                32,768
#define OFF_MASK  2162688UL    // uint mask[256][8192]         8,388,608
#define WS_NEEDED 10551296UL

#define ROW_CAP  256   // max neighbors/row (mean 82; 19-sigma headroom)

typedef float  floatx4 __attribute__((ext_vector_type(4)));
typedef unsigned int    uintx4  __attribute__((ext_vector_type(4)));
typedef unsigned short  ushortx8 __attribute__((ext_vector_type(8)));

__device__ __forceinline__ unsigned short f2bf(float f) {  // RNE
    unsigned int u = __builtin_bit_cast(unsigned int, f);
    u += 0x7fffu + ((u >> 16) & 1u);
    return (unsigned short)(u >> 16);
}
__device__ __forceinline__ float bf2f(unsigned short s) {
    return __builtin_bit_cast(float, (unsigned int)s << 16);
}

// ---------------------------------------------------------------------------
// K1 (block-role, small-LDS, 8 blocks/CU — verified R9 structure):
//   [0, 256)     gemm:  Hb = bf16(x W^T), 64x64 tiles, 8.7 KB LDS k-tiled
//   [256, 288)   alpha: asrc = x (W^T att_s), adst = x (W^T att_d)
//   [288, 2336)  sparsify: adj -> bitmasks, NONTEMPORAL (read-once stream)
// ---------------------------------------------------------------------------
__global__ __launch_bounds__(256, 8) void k_phase1(
    const float* __restrict__ x, const float* __restrict__ adj,
    const float* __restrict__ w, const float* __restrict__ att_s,
    const float* __restrict__ att_d, unsigned short* __restrict__ Hb,
    float* __restrict__ asrc, float* __restrict__ adst,
    unsigned int* __restrict__ mask)
{
    __shared__ union {
        struct { float xa[64][17]; float wb[16][68]; } g;   // 8704 B
        struct { float vs[128]; float vd[128]; } a;         // 1024 B
    } sm;

    const int tid = threadIdx.x;
    const int b   = blockIdx.x;

    if (b < 256) {
        // ---------------- gemm (verified R8/R9 body) -----------------------
        const int i0g = (b >> 1) * 64;
        const int o0  = (b & 1) * 64;
        const int tx  = tid & 15;
        const int ty  = tid >> 4;
        float acc[4][4];
#pragma unroll
        for (int i = 0; i < 4; ++i)
#pragma unroll
            for (int j = 0; j < 4; ++j) acc[i][j] = 0.f;

        for (int kt = 0; kt < 8; ++kt) {   // 8 k-tiles of 16
            __syncthreads();
            {
                const int r  = tid >> 2;
                const int kq = tid & 3;
                float4 v = *reinterpret_cast<const float4*>(
                    x + (size_t)(i0g + r) * DIM + kt * 16 + kq * 4);
                sm.g.xa[r][kq * 4 + 0] = v.x;
                sm.g.xa[r][kq * 4 + 1] = v.y;
                sm.g.xa[r][kq * 4 + 2] = v.z;
                sm.g.xa[r][kq * 4 + 3] = v.w;
            }
            {
                const int o  = tid & 63;
                const int kq = tid >> 6;
                float4 v = *reinterpret_cast<const float4*>(
                    w + (size_t)(o0 + o) * DIM + kt * 16 + kq * 4);
                sm.g.wb[kq * 4 + 0][o] = v.x;
                sm.g.wb[kq * 4 + 1][o] = v.y;
                sm.g.wb[kq * 4 + 2][o] = v.z;
                sm.g.wb[kq * 4 + 3][o] = v.w;
            }
            __syncthreads();
#pragma unroll
            for (int kk = 0; kk < 16; ++kk) {
                float4 wv4 = *reinterpret_cast<const float4*>(&sm.g.wb[kk][tx * 4]);
#pragma unroll
                for (int i = 0; i < 4; ++i) {
                    const float xv = sm.g.xa[ty * 4 + i][kk];
                    acc[i][0] += xv * wv4.x;
                    acc[i][1] += xv * wv4.y;
                    acc[i][2] += xv * wv4.z;
                    acc[i][3] += xv * wv4.w;
                }
            }
        }
#pragma unroll
        for (int i = 0; i < 4; ++i) {
            ushort4 h4;
            h4.x = f2bf(acc[i][0]);
            h4.y = f2bf(acc[i][1]);
            h4.z = f2bf(acc[i][2]);
            h4.w = f2bf(acc[i][3]);
            *reinterpret_cast<ushort4*>(
                Hb + (size_t)(i0g + ty * 4 + i) * DIM + o0 + tx * 4) = h4;
        }

    } else if (b < 288) {
        // ---------------- alpha (verified R8/R9 body) ----------------------
        const int t = b - 256;
        {
            const int is_d = tid >> 7;
            const int k    = tid & 127;
            const float* av = is_d ? att_d : att_s;
            float acc = 0.f;
            for (int o = 0; o < 128; ++o)
                acc += w[(size_t)o * 128 + k] * av[o];
            (is_d ? sm.a.vd : sm.a.vs)[k] = acc;
        }
        __syncthreads();
        const int r = t * 256 + tid;
        const float4* xr = reinterpret_cast<const float4*>(x + (size_t)r * DIM);
        float ss = 0.f, dd = 0.f;
#pragma unroll 8
        for (int q = 0; q < 32; ++q) {
            float4 xv = xr[q];
#pragma unroll
            for (int e = 0; e < 4; ++e) {
                const int k = q * 4 + e;
                const float xk = (&xv.x)[e];
                ss += xk * sm.a.vs[k];
                dd += xk * sm.a.vd[k];
            }
        }
        asrc[r] = ss;
        adst[r] = dd;

    } else {
        // ---------------- sparsify: nontemporal read-once stream -----------
        const int s  = b - 288;            // 0..2047
        const int ct = s & 7;
        const int g  = s >> 3;
        const int i0 = ct * 1024 + tid * 4;
        const float* base = adj + (size_t)(g * 32) * NN + i0;

        unsigned int m0 = 0, m1 = 0, m2 = 0, m3 = 0;
#pragma unroll 2
        for (int jj = 0; jj < 32; jj += 4) {
            const float* p = base + (size_t)jj * NN;
            floatx4 v0 = __builtin_nontemporal_load(reinterpret_cast<const floatx4*>(p));
            floatx4 v1 = __builtin_nontemporal_load(reinterpret_cast<const floatx4*>(p + NN));
            floatx4 v2 = __builtin_nontemporal_load(reinterpret_cast<const floatx4*>(p + 2 * NN));
            floatx4 v3 = __builtin_nontemporal_load(reinterpret_cast<const floatx4*>(p + 3 * NN));
#define PROC(v, dj)                                             \
            {                                                   \
                const unsigned int bb = 1u << (jj + (dj));      \
                if (v.x != 0.f) m0 |= bb;                       \
                if (v.y != 0.f) m1 |= bb;                       \
                if (v.z != 0.f) m2 |= bb;                       \
                if (v.w != 0.f) m3 |= bb;                       \
            }
            PROC(v0, 0) PROC(v1, 1) PROC(v2, 2) PROC(v3, 3)
#undef PROC
        }
        uintx4 mv;
        mv.x = m0; mv.y = m1; mv.z = m2; mv.w = m3;
        __builtin_nontemporal_store(mv,
            reinterpret_cast<uintx4*>(mask + (size_t)g * NN + i0));
    }
}

// ---------------------------------------------------------------------------
// K2 gather (R9 verified skeleton; gather loop upgraded to 4-neighbor):
// 1024 blocks x 8 rows, XCD-chunked; transposed mask tile in LDS; per wave
// x 2 rows: popcount -> scan -> ctz extract -> exp weights -> butterfly
// denom -> 4-NEIGHBOR gather: lane group g=lane>>4 handles neighbor k+g via
// ushort8 (16 B) bf16 loads (16 lanes cover the 256 B row); reduce with
// shfl_xor(16) + shfl_xor(32).
// ---------------------------------------------------------------------------
__global__ __launch_bounds__(256, 8) void k_gather(
    const unsigned int* __restrict__ mask, const unsigned short* __restrict__ Hb,
    const float* __restrict__ asrc, const float* __restrict__ adst,
    float* __restrict__ out)
{
    __shared__ unsigned int mt[8][256];          // 8192 B
    __shared__ int   s_jl[4][260];               // 4160 B
    __shared__ float s_wl[4][260];               // 4160 B

    const int tid  = threadIdx.x;
    const int b    = blockIdx.x;
    const int lane = tid & 63;
    const int wv   = tid >> 6;
    const int i0 = (((b & 7) << 7) | (b >> 3)) * 8;   // XCD-chunked rows

    // transposed mask tile: mt[ii][g]
#pragma unroll
    for (int p = 0; p < 2; ++p) {
        const int q   = p * 256 + tid;      // 0..511
        const int g   = q >> 1;
        const int ii4 = (q & 1) * 4;
        uint4 v = *reinterpret_cast<const uint4*>(mask + (size_t)g * NN + i0 + ii4);
        mt[ii4 + 0][g] = v.x;
        mt[ii4 + 1][g] = v.y;
        mt[ii4 + 2][g] = v.z;
        mt[ii4 + 3][g] = v.w;
    }
    __syncthreads();

    int* const   jl = s_jl[wv];
    float* const wl = s_wl[wv];

    for (int rr = 0; rr < 2; ++rr) {
        const int ii = wv * 2 + rr;
        const int i  = i0 + ii;

        uint4 mv = *reinterpret_cast<const uint4*>(&mt[ii][4 * lane]);
        const int csum = __popc(mv.x) + __popc(mv.y) + __popc(mv.z) + __popc(mv.w);

        int incl = csum;
#pragma unroll
        for (int off = 1; off < 64; off <<= 1) {
            int tt = __shfl_up(incl, off);
            if (lane >= off) incl += tt;
        }
        const int cnt = min(__shfl(incl, 63), ROW_CAP);
        int off = incl - csum;

#define EXTRACT(mm, q)                                                  \
        {                                                               \
            unsigned int z = (mm);                                      \
            const int jb = (4 * lane + (q)) * 32;                       \
            while (z) {                                                 \
                const int bb = __builtin_ctz(z);                        \
                z &= z - 1;                                             \
                if (off < ROW_CAP) jl[off] = jb + bb;                   \
                ++off;                                                  \
            }                                                           \
        }
        EXTRACT(mv.x, 0) EXTRACT(mv.y, 1) EXTRACT(mv.z, 2) EXTRACT(mv.w, 3)
#undef EXTRACT
        __builtin_amdgcn_wave_barrier();

        // weights + denominator
        const float adst_i = adst[i];
        float dsum = 0.f;
        for (int t = lane; t < cnt; t += 64) {
            const float cv = asrc[jl[t]] + adst_i;
            const float wgt = __expf(fmaxf(0.2f * cv, cv));
            wl[t] = wgt;
            dsum += wgt;
        }
#pragma unroll
        for (int mo = 1; mo < 64; mo <<= 1) dsum += __shfl_xor(dsum, mo);
        const float inv = 1.f / dsum;       // self-loops guarantee > 0

        // pad to multiple of 4 (pad slots weight 0)
        if (lane == 0) {
            const int cnt4l = (cnt + 3) & ~3;
            for (int e = cnt; e < cnt4l; ++e) { jl[e] = i; wl[e] = 0.f; }
        }
        __builtin_amdgcn_wave_barrier();
        const int cnt4 = (cnt + 3) & ~3;

        // 4-neighbor gather: group = lane>>4 owns neighbor k+group;
        // 16 lanes/group x ushort8 cover the full 256 B bf16 row.
        const int grp = lane >> 4;
        const int l16 = lane & 15;
        float a0 = 0.f, a1 = 0.f, a2 = 0.f, a3 = 0.f;
        float a4 = 0.f, a5 = 0.f, a6 = 0.f, a7 = 0.f;
        for (int k = 0; k < cnt4; k += 4) {
            const int   j  = jl[k + grp];
            const float ww = wl[k + grp];
            ushortx8 h = *reinterpret_cast<const ushortx8*>(
                Hb + (size_t)j * DIM + l16 * 8);
            a0 += ww * bf2f(h.s0);
            a1 += ww * bf2f(h.s1);
            a2 += ww * bf2f(h.s2);
            a3 += ww * bf2f(h.s3);
            a4 += ww * bf2f(h.s4);
            a5 += ww * bf2f(h.s5);
            a6 += ww * bf2f(h.s6);
            a7 += ww * bf2f(h.s7);
        }
#pragma unroll
        for (int m = 16; m <= 32; m <<= 1) {
            a0 += __shfl_xor(a0, m);
            a1 += __shfl_xor(a1, m);
            a2 += __shfl_xor(a2, m);
            a3 += __shfl_xor(a3, m);
            a4 += __shfl_xor(a4, m);
            a5 += __shfl_xor(a5, m);
            a6 += __shfl_xor(a6, m);
            a7 += __shfl_xor(a7, m);
        }
        if (grp == 0) {
            float* op = out + (size_t)i * DIM + l16 * 8;
            *reinterpret_cast<float4*>(op)     = make_float4(a0*inv, a1*inv, a2*inv, a3*inv);
            *reinterpret_cast<float4*>(op + 4) = make_float4(a4*inv, a5*inv, a6*inv, a7*inv);
        }
    }
}

extern "C" void kernel_launch(void* const* d_in, const int* in_sizes, int n_in,
                              void* d_out, int out_size, void* d_ws, size_t ws_size,
                              hipStream_t stream)
{
    const float* x     = (const float*)d_in[0];
    const float* adj   = (const float*)d_in[1];
    const float* w     = (const float*)d_in[2];
    const float* att_s = (const float*)d_in[3];
    const float* att_d = (const float*)d_in[4];
    float* out = (float*)d_out;

    if (ws_size < WS_NEEDED) return;  // loud failure (output stays poisoned)

    char* ws = (char*)d_ws;
    unsigned short* Hb   = (unsigned short*)(ws + OFF_HB);
    float*          asrc = (float*)(ws + OFF_ASRC);
    float*          adst = (float*)(ws + OFF_ADST);
    unsigned int*   mask = (unsigned int*)(ws + OFF_MASK);

    k_phase1<<<2336, 256, 0, stream>>>(x, adj, w, att_s, att_d, Hb, asrc, adst, mask);
    k_gather<<<1024, 256, 0, stream>>>(mask, Hb, asrc, adst, out);
}